// Round 1
// baseline (754.966 us; speedup 1.0000x reference)
//
#include <hip/hip_runtime.h>

// LSTM cell, B=8192, IN=H=2048, fp32 in/out.
// Strategy: pack x|h -> X2 bf16 [8192][4096], weights -> W2 bf16 [4*2048][4096]
// (gate-major, K-concatenated). One fused NT-GEMM kernel computes, per block,
// a 128-row x 32-col tile of ALL FOUR gates (B-tile rows = 4 gates x 32 cols),
// then applies the LSTM elementwise epilogue in-register and writes h_new,c_new.

typedef __attribute__((ext_vector_type(8))) short short8;
typedef __attribute__((ext_vector_type(8))) __bf16 bf16x8;
typedef __attribute__((ext_vector_type(4))) float f32x4;

#define GLDS(gp, lp)                                                        \
  __builtin_amdgcn_global_load_lds(                                         \
      (const __attribute__((address_space(1))) void*)(gp),                  \
      (__attribute__((address_space(3))) void*)(lp), 16, 0, 0)

__device__ __forceinline__ unsigned short f2bf(float f) {
  unsigned u = __builtin_bit_cast(unsigned, f);
  u = (u + 0x7FFFu + ((u >> 16) & 1u)) >> 16;  // round-to-nearest-even
  return (unsigned short)u;
}

// ---- pack [x | h] -> X2 bf16 [8192][4096] ----
__global__ void pack_x_kernel(const float* __restrict__ x,
                              const float* __restrict__ h,
                              short* __restrict__ X2) {
  long tid = (long)blockIdx.x * blockDim.x + threadIdx.x;
  long flat = tid * 8;
  int row = (int)(flat >> 12);
  int k = (int)(flat & 4095);
  const float* src = (k < 2048) ? (x + (long)row * 2048 + k)
                                : (h + (long)row * 2048 + (k - 2048));
  float4 a = *(const float4*)src;
  float4 b = *(const float4*)(src + 4);
  short8 o;
  o[0] = (short)f2bf(a.x); o[1] = (short)f2bf(a.y);
  o[2] = (short)f2bf(a.z); o[3] = (short)f2bf(a.w);
  o[4] = (short)f2bf(b.x); o[5] = (short)f2bf(b.y);
  o[6] = (short)f2bf(b.z); o[7] = (short)f2bf(b.w);
  *(short8*)(X2 + flat) = o;
}

// ---- pack weights -> W2 bf16 [gate*2048 + j][4096] = [w_xg[j] | w_hg[j]] ----
__global__ void pack_w_kernel(const float* __restrict__ wxf, const float* __restrict__ wxi,
                              const float* __restrict__ wxo, const float* __restrict__ wxc,
                              const float* __restrict__ whf, const float* __restrict__ whi,
                              const float* __restrict__ who, const float* __restrict__ whc,
                              short* __restrict__ W2) {
  long tid = (long)blockIdx.x * blockDim.x + threadIdx.x;
  long flat = tid * 8;
  int row = (int)(flat >> 12);
  int k = (int)(flat & 4095);
  int g = row >> 11;
  int j = row & 2047;
  const float* base;
  if (k < 2048) {
    const float* wx = (g == 0) ? wxf : (g == 1) ? wxi : (g == 2) ? wxo : wxc;
    base = wx + (long)j * 2048 + k;
  } else {
    const float* wh = (g == 0) ? whf : (g == 1) ? whi : (g == 2) ? who : whc;
    base = wh + (long)j * 2048 + (k - 2048);
  }
  float4 a = *(const float4*)base;
  float4 b = *(const float4*)(base + 4);
  short8 o;
  o[0] = (short)f2bf(a.x); o[1] = (short)f2bf(a.y);
  o[2] = (short)f2bf(a.z); o[3] = (short)f2bf(a.w);
  o[4] = (short)f2bf(b.x); o[5] = (short)f2bf(b.y);
  o[6] = (short)f2bf(b.z); o[7] = (short)f2bf(b.w);
  *(short8*)(W2 + flat) = o;
}

// ---- fused GEMM + LSTM epilogue ----
// Block tile: 128 batch-rows x 32 hidden-cols x 4 gates. K = 4096, BK = 32.
// 4 waves (2 row-halves x 2 col-halves). Per wave: 4 m-frags x 4 gate-frags.
__global__ __launch_bounds__(256) void lstm_fused_gemm(
    const short* __restrict__ X2, const short* __restrict__ W2,
    const float* __restrict__ cin,
    const float* __restrict__ bfv, const float* __restrict__ biv,
    const float* __restrict__ bov, const float* __restrict__ bcv,
    float* __restrict__ hout, float* __restrict__ cout_) {
  __shared__ __align__(16) short As[128 * 32];
  __shared__ __align__(16) short Bs[128 * 32];

  const int tid = threadIdx.x;
  const int w = tid >> 6;
  const int l = tid & 63;
  const int wr = w >> 1, wc = w & 1;
  const int brow = blockIdx.x;   // 0..63 (batch blocks of 128)
  const int bcol = blockIdx.y;   // 0..63 (hidden blocks of 32)

  f32x4 acc[4][4] = {};          // [m][gate]

  // staging geometry: each wave stages 2x 16-row chunks of A and of B.
  // lane l -> row srow = l>>2 within chunk, 16B at k-offset (l&3)*8 elems.
  const int srow = l >> 2;
  const int skoff = (l & 3) * 8;

  const int ar0 = w * 32 + srow;        // tile rows (A and B share geometry)
  const int ar1 = w * 32 + 16 + srow;
  // B tile row r -> W2 row: gate = r>>5, col = bcol*32 + (r&31)
  const long w2r0 = (long)(ar0 >> 5) * 2048 + (long)bcol * 32 + (ar0 & 31);
  const long w2r1 = (long)(ar1 >> 5) * 2048 + (long)bcol * 32 + (ar1 & 31);

  const short* aG0 = X2 + ((long)brow * 128 + ar0) * 4096 + skoff;
  const short* aG1 = X2 + ((long)brow * 128 + ar1) * 4096 + skoff;
  const short* bG0 = W2 + w2r0 * 4096 + skoff;
  const short* bG1 = W2 + w2r1 * 4096 + skoff;

  short* aL0 = As + (w * 32 + 0) * 32;
  short* aL1 = As + (w * 32 + 16) * 32;
  short* bL0 = Bs + (w * 32 + 0) * 32;
  short* bL1 = Bs + (w * 32 + 16) * 32;

  const int lr = l & 15;          // fragment row/col within 16
  const int lk = (l >> 4) * 8;    // fragment k-offset (elems)

  for (int kt = 0; kt < 4096; kt += 32) {
    GLDS(aG0 + kt, aL0);
    GLDS(aG1 + kt, aL1);
    GLDS(bG0 + kt, bL0);
    GLDS(bG1 + kt, bL1);
    __syncthreads();

    bf16x8 af[4], bfr[4];
#pragma unroll
    for (int m = 0; m < 4; ++m)
      af[m] = *(const bf16x8*)&As[(wr * 64 + m * 16 + lr) * 32 + lk];
#pragma unroll
    for (int g = 0; g < 4; ++g)
      bfr[g] = *(const bf16x8*)&Bs[(g * 32 + wc * 16 + lr) * 32 + lk];

#pragma unroll
    for (int m = 0; m < 4; ++m)
#pragma unroll
      for (int g = 0; g < 4; ++g)
        acc[m][g] = __builtin_amdgcn_mfma_f32_16x16x32_bf16(af[m], bfr[g],
                                                            acc[m][g], 0, 0, 0);
    __syncthreads();
  }

  // Epilogue: lane holds C[row=(l>>4)*4+r + m*16][col=lr] for each gate.
  const int col = bcol * 32 + wc * 16 + lr;
  const float vbf = bfv[col], vbi = biv[col], vbo = bov[col], vbc = bcv[col];
  const int rbase = brow * 128 + wr * 64 + (l >> 4) * 4;
#pragma unroll
  for (int m = 0; m < 4; ++m) {
#pragma unroll
    for (int r = 0; r < 4; ++r) {
      const long grow = rbase + m * 16 + r;
      float gf = acc[m][0][r] + vbf;
      float gi = acc[m][1][r] + vbi;
      float go = acc[m][2][r] + vbo;
      float gc = acc[m][3][r] + vbc;
      float fg = 1.f / (1.f + __expf(-gf));
      float ig = 1.f / (1.f + __expf(-gi));
      float og = 1.f / (1.f + __expf(-go));
      float ct = tanhf(gc);
      float cn = fg * cin[grow * 2048 + col] + ig * ct;
      float hn = og * tanhf(cn);
      hout[grow * 2048 + col] = hn;
      cout_[grow * 2048 + col] = cn;
    }
  }
}

extern "C" void kernel_launch(void* const* d_in, const int* in_sizes, int n_in,
                              void* d_out, int out_size, void* d_ws, size_t ws_size,
                              hipStream_t stream) {
  const float* x    = (const float*)d_in[0];
  const float* h    = (const float*)d_in[1];
  const float* c    = (const float*)d_in[2];
  const float* w_xf = (const float*)d_in[3];
  const float* w_hf = (const float*)d_in[4];
  const float* b_f  = (const float*)d_in[5];
  const float* w_xi = (const float*)d_in[6];
  const float* w_hi = (const float*)d_in[7];
  const float* b_i  = (const float*)d_in[8];
  const float* w_xo = (const float*)d_in[9];
  const float* w_ho = (const float*)d_in[10];
  const float* b_o  = (const float*)d_in[11];
  const float* w_xc = (const float*)d_in[12];
  const float* w_hc = (const float*)d_in[13];
  const float* b_c  = (const float*)d_in[14];

  float* hout  = (float*)d_out;
  float* cout_ = hout + (size_t)8192 * 2048;

  short* X2 = (short*)d_ws;                       // 8192*4096 bf16 = 64 MiB
  short* W2 = X2 + (size_t)8192 * 4096;           // 8192*4096 bf16 = 64 MiB

  const int packBlocks = (int)(((long)8192 * 4096 / 8) / 256);  // 16384
  pack_x_kernel<<<packBlocks, 256, 0, stream>>>(x, h, X2);
  pack_w_kernel<<<packBlocks, 256, 0, stream>>>(w_xf, w_xi, w_xo, w_xc,
                                                w_hf, w_hi, w_ho, w_hc, W2);

  dim3 grid(64, 64);
  lstm_fused_gemm<<<grid, 256, 0, stream>>>(X2, W2, c, b_f, b_i, b_o, b_c,
                                            hout, cout_);
}

// Round 2
// 649.255 us; speedup vs baseline: 1.1628x; 1.1628x over previous
//
#include <hip/hip_runtime.h>

// LSTM cell, B=8192, IN=H=2048, fp32 in/out.
// Round 2: 256x256 8-phase counted-vmcnt GEMM (T1+T2+T3+T4+T5), fused LSTM epilogue.
// Pack: X2 bf16 [8192][4096] = [x|h];  W3 bf16 [8192][4096] with row
//   j = (hc>>4)*64 + gate*16 + (hc&15)  -> per-wave n-fragment == gate.

typedef __attribute__((ext_vector_type(8))) short short8;
typedef __attribute__((ext_vector_type(8))) __bf16 bf16x8;
typedef __attribute__((ext_vector_type(4))) float f32x4;

#define GLDS(gp, lp)                                                        \
  __builtin_amdgcn_global_load_lds(                                         \
      (const __attribute__((address_space(1))) void*)(gp),                  \
      (__attribute__((address_space(3))) void*)(lp), 16, 0, 0)

__device__ __forceinline__ unsigned short f2bf(float f) {
  unsigned u = __builtin_bit_cast(unsigned, f);
  u = (u + 0x7FFFu + ((u >> 16) & 1u)) >> 16;  // RNE
  return (unsigned short)u;
}

// ---- pack [x | h] -> X2 bf16 [8192][4096] ----
__global__ void pack_x_kernel(const float* __restrict__ x,
                              const float* __restrict__ h,
                              short* __restrict__ X2) {
  long tid = (long)blockIdx.x * blockDim.x + threadIdx.x;
  long flat = tid * 8;
  int row = (int)(flat >> 12);
  int k = (int)(flat & 4095);
  const float* src = (k < 2048) ? (x + (long)row * 2048 + k)
                                : (h + (long)row * 2048 + (k - 2048));
  float4 a = *(const float4*)src;
  float4 b = *(const float4*)(src + 4);
  short8 o;
  o[0] = (short)f2bf(a.x); o[1] = (short)f2bf(a.y);
  o[2] = (short)f2bf(a.z); o[3] = (short)f2bf(a.w);
  o[4] = (short)f2bf(b.x); o[5] = (short)f2bf(b.y);
  o[6] = (short)f2bf(b.z); o[7] = (short)f2bf(b.w);
  *(short8*)(X2 + flat) = o;
}

// ---- pack weights -> W3 bf16 [8192][4096]; row j: hc=(j>>6)*16+(j&15), g=(j>>4)&3 ----
__global__ void pack_w_kernel(const float* __restrict__ wxf, const float* __restrict__ wxi,
                              const float* __restrict__ wxo, const float* __restrict__ wxc,
                              const float* __restrict__ whf, const float* __restrict__ whi,
                              const float* __restrict__ who, const float* __restrict__ whc,
                              short* __restrict__ W3) {
  long tid = (long)blockIdx.x * blockDim.x + threadIdx.x;
  long flat = tid * 8;
  int j = (int)(flat >> 12);
  int k = (int)(flat & 4095);
  int hc = ((j >> 6) << 4) | (j & 15);
  int g = (j >> 4) & 3;
  const float* base;
  if (k < 2048) {
    const float* wx = (g == 0) ? wxf : (g == 1) ? wxi : (g == 2) ? wxo : wxc;
    base = wx + (long)hc * 2048 + k;
  } else {
    const float* wh = (g == 0) ? whf : (g == 1) ? whi : (g == 2) ? who : whc;
    base = wh + (long)hc * 2048 + (k - 2048);
  }
  float4 a = *(const float4*)base;
  float4 b = *(const float4*)(base + 4);
  short8 o;
  o[0] = (short)f2bf(a.x); o[1] = (short)f2bf(a.y);
  o[2] = (short)f2bf(a.z); o[3] = (short)f2bf(a.w);
  o[4] = (short)f2bf(b.x); o[5] = (short)f2bf(b.y);
  o[6] = (short)f2bf(b.z); o[7] = (short)f2bf(b.w);
  *(short8*)(W3 + flat) = o;
}

// ---- 256x256 8-phase fused GEMM + LSTM epilogue ----
// LDS: 2 buffers x {A-kh0, B-kh0, A-kh1, B-kh1} x 16KB. Each region [256 rows][32 bf16],
// 16B-chunk swizzle: slot ^= (r>>1)&3 (involution; applied on global src + ds_read).
__global__ __launch_bounds__(512, 2) void lstm_fused_gemm(
    const short* __restrict__ X2, const short* __restrict__ W3,
    const float* __restrict__ cin,
    const float* __restrict__ bF, const float* __restrict__ bI,
    const float* __restrict__ bO, const float* __restrict__ bC,
    float* __restrict__ hout, float* __restrict__ cout_) {
  __shared__ __align__(16) short lds[65536];  // 128 KiB

  const int tid = threadIdx.x;
  const int lane = tid & 63;
  const int w = tid >> 6;        // 0..7
  const int wm = w >> 2;         // 0..1  (M half)
  const int wn = w & 3;          // 0..3  (N quarter)

  // T1: XCD-aware swizzle; 1024 blocks, 1024%8==0 -> simple form is bijective.
  const int bid = blockIdx.x;
  const int wg = (bid & 7) * 128 + (bid >> 3);
  const int bM = wg >> 5;        // 0..31
  const int bN = wg & 31;        // 0..31

  // --- staging geometry: chunk ci covers region row r=ci>>2, slot ci&3 (16B) ---
  const int ci = w * 64 + lane;                 // load L adds 512 (rows +128)
  const int r0 = ci >> 2;                       // 0..127
  const int ss = (ci & 3) ^ ((r0 >> 1) & 3);    // pre-swizzled source slot
  const short* aRow0 = X2 + ((size_t)(bM * 256 + r0)) * 4096 + ss * 8;
  const short* aRow1 = aRow0 + (size_t)128 * 4096;
  const short* bRow0 = W3 + ((size_t)(bN * 256 + r0)) * 4096 + ss * 8;
  const short* bRow1 = bRow0 + (size_t)128 * 4096;
  const int wOff = w * 1024;

#define STAGE2(q, tt, bb) do {                                               \
    const int _kh = (q) >> 1;                                                \
    const short* _g0; const short* _g1;                                      \
    if ((q) == 0 || (q) == 2) {                                              \
      _g0 = aRow0 + (tt) * 64 + _kh * 32;                                    \
      _g1 = aRow1 + (tt) * 64 + _kh * 32;                                    \
    } else {                                                                 \
      _g0 = bRow0 + (tt) * 64 + _kh * 32;                                    \
      _g1 = bRow1 + (tt) * 64 + _kh * 32;                                    \
    }                                                                        \
    char* _l0 = (char*)lds + (bb) * 65536 + (q) * 16384 + wOff;              \
    GLDS(_g0, _l0);                                                          \
    GLDS(_g1, _l0 + 8192);                                                   \
  } while (0)

  // --- ds_read geometry (swizzle depends only on lane bits -> per-lane const) ---
  const int lr = lane & 15, hi = lane >> 4;
  const int swz = ((hi ^ ((lr >> 1) & 3)) << 4);
  const int aoff = wm * 8192 + lr * 64 + swz;          // + m*1024 + kk*32768 + buf*65536
  const int boff = 16384 + wn * 4096 + lr * 64 + swz;  // + n*1024 + kk*32768 + buf*65536

#define LDSRD(off) (*(const bf16x8*)((const char*)lds + (off)))
#define MFMA_(a, b, c) __builtin_amdgcn_mfma_f32_16x16x32_bf16((a), (b), (c), 0, 0, 0)

  f32x4 acc[8][4] = {};  // [m 0..7][n==gate 0..3]

  // --- prologue: tile0 q0-q3 + tile1 q0-q2 (14 loads), wait oldest 8 ---
  STAGE2(0, 0, 0); STAGE2(1, 0, 0); STAGE2(2, 0, 0); STAGE2(3, 0, 0);
  STAGE2(0, 1, 1); STAGE2(1, 1, 1); STAGE2(2, 1, 1);
  asm volatile("s_waitcnt vmcnt(6)" ::: "memory");
  __builtin_amdgcn_s_barrier();

#pragma unroll 2
  for (int t = 0; t < 64; ++t) {
    const int cur = t & 1, nxt = cur ^ 1;
    const int bo = cur << 16;
    const int t1 = (t + 1) & 63;   // wrapped dummy stages keep vmcnt uniform;
    const int t2 = (t + 2) & 63;   // they land in buffers never read again.
    bf16x8 a0[8], a1[8];

    // ---- phase 0: read A kk0 + B kk0 n0-1; stage q3(t+1)->nxt; MFMA kk0 n0-1
#pragma unroll
    for (int m = 0; m < 8; ++m) a0[m] = LDSRD(bo + aoff + m * 1024);
    bf16x8 bq0 = LDSRD(bo + boff + 0 * 1024);
    bf16x8 bq1 = LDSRD(bo + boff + 1 * 1024);
    STAGE2(3, t1, nxt);
    __builtin_amdgcn_s_barrier();
    asm volatile("s_waitcnt lgkmcnt(0)" ::: "memory");
    __builtin_amdgcn_sched_barrier(0);
    __builtin_amdgcn_s_setprio(1);
#pragma unroll
    for (int m = 0; m < 8; ++m) acc[m][0] = MFMA_(a0[m], bq0, acc[m][0]);
#pragma unroll
    for (int m = 0; m < 8; ++m) acc[m][1] = MFMA_(a0[m], bq1, acc[m][1]);
    __builtin_amdgcn_s_setprio(0);
    __builtin_amdgcn_s_barrier();

    // ---- phase 1: read B kk0 n2-3 + A kk1; stage q0(t+2)->cur; MFMA kk0 n2-3
    bf16x8 bq2 = LDSRD(bo + boff + 2 * 1024);
    bf16x8 bq3 = LDSRD(bo + boff + 3 * 1024);
#pragma unroll
    for (int m = 0; m < 8; ++m) a1[m] = LDSRD(bo + aoff + 32768 + m * 1024);
    STAGE2(0, t2, cur);
    __builtin_amdgcn_s_barrier();
    asm volatile("s_waitcnt lgkmcnt(0)" ::: "memory");
    __builtin_amdgcn_sched_barrier(0);
    __builtin_amdgcn_s_setprio(1);
#pragma unroll
    for (int m = 0; m < 8; ++m) acc[m][2] = MFMA_(a0[m], bq2, acc[m][2]);
#pragma unroll
    for (int m = 0; m < 8; ++m) acc[m][3] = MFMA_(a0[m], bq3, acc[m][3]);
    __builtin_amdgcn_s_setprio(0);
    __builtin_amdgcn_s_barrier();

    // ---- phase 2: read B kk1 n0-1; stage q1(t+2)->cur; MFMA kk1 n0-1
    bf16x8 cq0 = LDSRD(bo + boff + 32768 + 0 * 1024);
    bf16x8 cq1 = LDSRD(bo + boff + 32768 + 1 * 1024);
    STAGE2(1, t2, cur);
    __builtin_amdgcn_s_barrier();
    asm volatile("s_waitcnt lgkmcnt(0)" ::: "memory");
    __builtin_amdgcn_sched_barrier(0);
    __builtin_amdgcn_s_setprio(1);
#pragma unroll
    for (int m = 0; m < 8; ++m) acc[m][0] = MFMA_(a1[m], cq0, acc[m][0]);
#pragma unroll
    for (int m = 0; m < 8; ++m) acc[m][1] = MFMA_(a1[m], cq1, acc[m][1]);
    __builtin_amdgcn_s_setprio(0);
    __builtin_amdgcn_s_barrier();

    // ---- phase 3: read B kk1 n2-3; stage q2(t+2)->cur; MFMA kk1 n2-3; vmcnt(6)
    bf16x8 cq2 = LDSRD(bo + boff + 32768 + 2 * 1024);
    bf16x8 cq3 = LDSRD(bo + boff + 32768 + 3 * 1024);
    STAGE2(2, t2, cur);
    __builtin_amdgcn_s_barrier();
    asm volatile("s_waitcnt lgkmcnt(0)" ::: "memory");
    __builtin_amdgcn_sched_barrier(0);
    __builtin_amdgcn_s_setprio(1);
#pragma unroll
    for (int m = 0; m < 8; ++m) acc[m][2] = MFMA_(a1[m], cq2, acc[m][2]);
#pragma unroll
    for (int m = 0; m < 8; ++m) acc[m][3] = MFMA_(a1[m], cq3, acc[m][3]);
    __builtin_amdgcn_s_setprio(0);
    asm volatile("s_waitcnt vmcnt(6)" ::: "memory");
    __builtin_amdgcn_s_barrier();
  }

  // ---- fused LSTM epilogue: gate g == fragment n; per-lane, 64B-coalesced ----
  const int hc = bN * 64 + wn * 16 + lr;
  const float vbf = bF[hc], vbi = bI[hc], vbo = bO[hc], vbc = bC[hc];
#pragma unroll
  for (int m = 0; m < 8; ++m) {
    const int rbase = bM * 256 + wm * 128 + m * 16 + hi * 4;
#pragma unroll
    for (int v = 0; v < 4; ++v) {
      const size_t idx = (size_t)(rbase + v) * 2048 + hc;
      float gf = acc[m][0][v] + vbf;
      float gi = acc[m][1][v] + vbi;
      float go = acc[m][2][v] + vbo;
      float gc = acc[m][3][v] + vbc;
      float fg = 1.f / (1.f + __expf(-gf));
      float ig = 1.f / (1.f + __expf(-gi));
      float og = 1.f / (1.f + __expf(-go));
      float ct = 2.f / (1.f + __expf(-2.f * gc)) - 1.f;
      float cn = fg * cin[idx] + ig * ct;
      float hn = og * (2.f / (1.f + __expf(-2.f * cn)) - 1.f);
      hout[idx] = hn;
      cout_[idx] = cn;
    }
  }
}

extern "C" void kernel_launch(void* const* d_in, const int* in_sizes, int n_in,
                              void* d_out, int out_size, void* d_ws, size_t ws_size,
                              hipStream_t stream) {
  const float* x    = (const float*)d_in[0];
  const float* h    = (const float*)d_in[1];
  const float* c    = (const float*)d_in[2];
  const float* w_xf = (const float*)d_in[3];
  const float* w_hf = (const float*)d_in[4];
  const float* b_f  = (const float*)d_in[5];
  const float* w_xi = (const float*)d_in[6];
  const float* w_hi = (const float*)d_in[7];
  const float* b_i  = (const float*)d_in[8];
  const float* w_xo = (const float*)d_in[9];
  const float* w_ho = (const float*)d_in[10];
  const float* b_o  = (const float*)d_in[11];
  const float* w_xc = (const float*)d_in[12];
  const float* w_hc = (const float*)d_in[13];
  const float* b_c  = (const float*)d_in[14];

  float* hout  = (float*)d_out;
  float* cout_ = hout + (size_t)8192 * 2048;

  short* X2 = (short*)d_ws;                       // 64 MiB
  short* W3 = X2 + (size_t)8192 * 4096;           // 64 MiB

  const int packBlocks = (int)(((long)8192 * 4096 / 8) / 256);  // 16384
  pack_x_kernel<<<packBlocks, 256, 0, stream>>>(x, h, X2);
  pack_w_kernel<<<packBlocks, 256, 0, stream>>>(w_xf, w_xi, w_xo, w_xc,
                                                w_hf, w_hi, w_ho, w_hc, W3);

  lstm_fused_gemm<<<1024, 512, 0, stream>>>(X2, W3, c, b_f, b_i, b_o, b_c,
                                            hout, cout_);
}

// Round 3
// 645.933 us; speedup vs baseline: 1.1688x; 1.0051x over previous
//
#include <hip/hip_runtime.h>

// LSTM cell, B=8192, IN=H=2048, fp32 in/out.
// Round 3: 256x256 8-phase GEMM with ds_read pipelined ONE PHASE AHEAD via
// counted lgkmcnt (overlap LDS service with MFMA issue), counted vmcnt,
// XCD swizzle, LDS XOR swizzle, setprio. Fused LSTM epilogue.
// Pack: X2 bf16 [8192][4096] = [x|h];  W3 bf16 [8192][4096] with row
//   j = (hc>>4)*64 + gate*16 + (hc&15)  -> per-wave n-fragment == gate.

typedef __attribute__((ext_vector_type(8))) short short8;
typedef __attribute__((ext_vector_type(8))) __bf16 bf16x8;
typedef __attribute__((ext_vector_type(4))) float f32x4;

#define GLDS(gp, lp)                                                        \
  __builtin_amdgcn_global_load_lds(                                         \
      (const __attribute__((address_space(1))) void*)(gp),                  \
      (__attribute__((address_space(3))) void*)(lp), 16, 0, 0)

__device__ __forceinline__ unsigned short f2bf(float f) {
  unsigned u = __builtin_bit_cast(unsigned, f);
  u = (u + 0x7FFFu + ((u >> 16) & 1u)) >> 16;  // RNE
  return (unsigned short)u;
}

// ---- pack [x | h] -> X2 bf16 [8192][4096] ----
__global__ void pack_x_kernel(const float* __restrict__ x,
                              const float* __restrict__ h,
                              short* __restrict__ X2) {
  long tid = (long)blockIdx.x * blockDim.x + threadIdx.x;
  long flat = tid * 8;
  int row = (int)(flat >> 12);
  int k = (int)(flat & 4095);
  const float* src = (k < 2048) ? (x + (long)row * 2048 + k)
                                : (h + (long)row * 2048 + (k - 2048));
  float4 a = *(const float4*)src;
  float4 b = *(const float4*)(src + 4);
  short8 o;
  o[0] = (short)f2bf(a.x); o[1] = (short)f2bf(a.y);
  o[2] = (short)f2bf(a.z); o[3] = (short)f2bf(a.w);
  o[4] = (short)f2bf(b.x); o[5] = (short)f2bf(b.y);
  o[6] = (short)f2bf(b.z); o[7] = (short)f2bf(b.w);
  *(short8*)(X2 + flat) = o;
}

// ---- pack weights -> W3 bf16 [8192][4096]; row j: hc=(j>>6)*16+(j&15), g=(j>>4)&3 ----
__global__ void pack_w_kernel(const float* __restrict__ wxf, const float* __restrict__ wxi,
                              const float* __restrict__ wxo, const float* __restrict__ wxc,
                              const float* __restrict__ whf, const float* __restrict__ whi,
                              const float* __restrict__ who, const float* __restrict__ whc,
                              short* __restrict__ W3) {
  long tid = (long)blockIdx.x * blockDim.x + threadIdx.x;
  long flat = tid * 8;
  int j = (int)(flat >> 12);
  int k = (int)(flat & 4095);
  int hc = ((j >> 6) << 4) | (j & 15);
  int g = (j >> 4) & 3;
  const float* base;
  if (k < 2048) {
    const float* wx = (g == 0) ? wxf : (g == 1) ? wxi : (g == 2) ? wxo : wxc;
    base = wx + (long)hc * 2048 + k;
  } else {
    const float* wh = (g == 0) ? whf : (g == 1) ? whi : (g == 2) ? who : whc;
    base = wh + (long)hc * 2048 + (k - 2048);
  }
  float4 a = *(const float4*)base;
  float4 b = *(const float4*)(base + 4);
  short8 o;
  o[0] = (short)f2bf(a.x); o[1] = (short)f2bf(a.y);
  o[2] = (short)f2bf(a.z); o[3] = (short)f2bf(a.w);
  o[4] = (short)f2bf(b.x); o[5] = (short)f2bf(b.y);
  o[6] = (short)f2bf(b.z); o[7] = (short)f2bf(b.w);
  *(short8*)(W3 + flat) = o;
}

// ---- 256x256 fused GEMM + LSTM epilogue ----
// LDS per buffer: q0 A-kh0 @0, q1 B-kh0 @16K, q2 A-kh1 @32K, q3 B-kh1 @48K.
// 16B-chunk swizzle: slot ^= (r>>1)&3 (involution on source + ds_read).
__global__ __launch_bounds__(512, 2) void lstm_fused_gemm(
    const short* __restrict__ X2, const short* __restrict__ W3,
    const float* __restrict__ cin,
    const float* __restrict__ bF, const float* __restrict__ bI,
    const float* __restrict__ bO, const float* __restrict__ bC,
    float* __restrict__ hout, float* __restrict__ cout_) {
  __shared__ __align__(16) short lds[65536];  // 128 KiB

  const int tid = threadIdx.x;
  const int lane = tid & 63;
  const int w = tid >> 6;        // 0..7
  const int wm = w >> 2;         // 0..1  (M half)
  const int wn = w & 3;          // 0..3  (N quarter)

  // T1: XCD-aware swizzle (1024 % 8 == 0 -> bijective).
  const int bid = blockIdx.x;
  const int wg = (bid & 7) * 128 + (bid >> 3);
  const int bM = wg >> 5;        // 0..31
  const int bN = wg & 31;        // 0..31

  // --- staging geometry ---
  const int ci = w * 64 + lane;
  const int r0 = ci >> 2;                       // 0..127
  const int ss = (ci & 3) ^ ((r0 >> 1) & 3);    // pre-swizzled source slot
  const short* aRow0 = X2 + ((size_t)(bM * 256 + r0)) * 4096 + ss * 8;
  const short* aRow1 = aRow0 + (size_t)128 * 4096;
  const short* bRow0 = W3 + ((size_t)(bN * 256 + r0)) * 4096 + ss * 8;
  const short* bRow1 = bRow0 + (size_t)128 * 4096;
  const int wOff = w * 1024;

#define STAGE2(q, tt, bb) do {                                               \
    const int _kh = (q) >> 1;                                                \
    const short* _g0; const short* _g1;                                      \
    if ((q) == 0 || (q) == 2) {                                              \
      _g0 = aRow0 + (tt) * 64 + _kh * 32;                                    \
      _g1 = aRow1 + (tt) * 64 + _kh * 32;                                    \
    } else {                                                                 \
      _g0 = bRow0 + (tt) * 64 + _kh * 32;                                    \
      _g1 = bRow1 + (tt) * 64 + _kh * 32;                                    \
    }                                                                        \
    char* _l0 = (char*)lds + (bb) * 65536 + (q) * 16384 + wOff;              \
    GLDS(_g0, _l0);                                                          \
    GLDS(_g1, _l0 + 8192);                                                   \
  } while (0)

  // --- ds_read geometry ---
  const int lr = lane & 15, hi = lane >> 4;
  const int swz = ((hi ^ ((lr >> 1) & 3)) << 4);
  const int aoff = wm * 8192 + lr * 64 + swz;          // + m*1024 + 32768 for kh1
  const int boff = 16384 + wn * 4096 + lr * 64 + swz;  // + n*1024 + 32768 for kh1

#define LDSRD(off) (*(const bf16x8*)((const char*)lds + (off)))
#define MFMA_(a, b, c) __builtin_amdgcn_mfma_f32_16x16x32_bf16((a), (b), (c), 0, 0, 0)

  f32x4 acc[8][4] = {};  // [m][n==gate]
  bf16x8 a0[8], b01[2]; // current tile kh0 operands (read one phase ahead)

  // --- prologue: tile0 q0-q3 + tile1 q0-q2 (14 GLDS), drain tile0, read r0 ---
  STAGE2(0, 0, 0); STAGE2(1, 0, 0); STAGE2(2, 0, 0); STAGE2(3, 0, 0);
  STAGE2(0, 1, 1); STAGE2(1, 1, 1); STAGE2(2, 1, 1);
  asm volatile("s_waitcnt vmcnt(6)" ::: "memory");
  __builtin_amdgcn_s_barrier();
#pragma unroll
  for (int m = 0; m < 8; ++m) a0[m] = LDSRD(aoff + m * 1024);
  b01[0] = LDSRD(boff + 0 * 1024);
  b01[1] = LDSRD(boff + 1 * 1024);

#pragma unroll 2
  for (int t = 0; t < 64; ++t) {
    const int cur = t & 1, nxt = cur ^ 1;
    const int bo = cur << 16, bon = nxt << 16;
    const int t1 = (t + 1) & 63;   // wrapped dummy stages keep vmcnt uniform
    const int t2 = (t + 2) & 63;

    // ---- ph0: issue b23 (for ph1); MFMA kk0 n0-1 (a0 x b01) ----
    bf16x8 b23_0 = LDSRD(bo + boff + 2 * 1024);
    bf16x8 b23_1 = LDSRD(bo + boff + 3 * 1024);
    STAGE2(3, t1, nxt);
    __builtin_amdgcn_s_barrier();
    asm volatile("s_waitcnt lgkmcnt(2)" ::: "memory");  // r0 done, b23 pending
    __builtin_amdgcn_sched_barrier(0);
    __builtin_amdgcn_s_setprio(1);
#pragma unroll
    for (int m = 0; m < 8; ++m) acc[m][0] = MFMA_(a0[m], b01[0], acc[m][0]);
#pragma unroll
    for (int m = 0; m < 8; ++m) acc[m][1] = MFMA_(a0[m], b01[1], acc[m][1]);
    __builtin_amdgcn_s_setprio(0);
    __builtin_amdgcn_s_barrier();

    // ---- ph1: issue a1 + c01 (for ph2); MFMA kk0 n2-3 (a0 x b23) ----
    bf16x8 a1[8];
#pragma unroll
    for (int m = 0; m < 8; ++m) a1[m] = LDSRD(bo + aoff + 32768 + m * 1024);
    bf16x8 c01_0 = LDSRD(bo + boff + 32768 + 0 * 1024);
    bf16x8 c01_1 = LDSRD(bo + boff + 32768 + 1 * 1024);
    STAGE2(0, t2, cur);
    __builtin_amdgcn_s_barrier();
    asm volatile("s_waitcnt lgkmcnt(10)" ::: "memory");  // b23 done, a1+c01 pending
    __builtin_amdgcn_sched_barrier(0);
    __builtin_amdgcn_s_setprio(1);
#pragma unroll
    for (int m = 0; m < 8; ++m) acc[m][2] = MFMA_(a0[m], b23_0, acc[m][2]);
#pragma unroll
    for (int m = 0; m < 8; ++m) acc[m][3] = MFMA_(a0[m], b23_1, acc[m][3]);
    __builtin_amdgcn_s_setprio(0);
    __builtin_amdgcn_s_barrier();

    // ---- ph2: issue c23 (for ph3); MFMA kk1 n0-1 (a1 x c01); vmcnt(8) ----
    bf16x8 c23_0 = LDSRD(bo + boff + 32768 + 2 * 1024);
    bf16x8 c23_1 = LDSRD(bo + boff + 32768 + 3 * 1024);
    STAGE2(1, t2, cur);
    __builtin_amdgcn_s_barrier();
    asm volatile("s_waitcnt lgkmcnt(2)" ::: "memory");  // a1+c01 done, c23 pending
    __builtin_amdgcn_sched_barrier(0);
    __builtin_amdgcn_s_setprio(1);
#pragma unroll
    for (int m = 0; m < 8; ++m) acc[m][0] = MFMA_(a1[m], c01_0, acc[m][0]);
#pragma unroll
    for (int m = 0; m < 8; ++m) acc[m][1] = MFMA_(a1[m], c01_1, acc[m][1]);
    __builtin_amdgcn_s_setprio(0);
    asm volatile("s_waitcnt vmcnt(8)" ::: "memory");  // next-tile q0,q1 landed
    __builtin_amdgcn_s_barrier();                     // ...visible to all waves

    // ---- ph3: issue next-tile a0+b01 (for next ph0); MFMA kk1 n2-3 ----
#pragma unroll
    for (int m = 0; m < 8; ++m) a0[m] = LDSRD(bon + aoff + m * 1024);
    b01[0] = LDSRD(bon + boff + 0 * 1024);
    b01[1] = LDSRD(bon + boff + 1 * 1024);
    STAGE2(2, t2, cur);
    __builtin_amdgcn_s_barrier();
    asm volatile("s_waitcnt lgkmcnt(10)" ::: "memory");  // c23 done, r0' pending
    __builtin_amdgcn_sched_barrier(0);
    __builtin_amdgcn_s_setprio(1);
#pragma unroll
    for (int m = 0; m < 8; ++m) acc[m][2] = MFMA_(a1[m], c23_0, acc[m][2]);
#pragma unroll
    for (int m = 0; m < 8; ++m) acc[m][3] = MFMA_(a1[m], c23_1, acc[m][3]);
    __builtin_amdgcn_s_setprio(0);
    asm volatile("s_waitcnt vmcnt(6)" ::: "memory");  // next-tile q2,q3 landed
    __builtin_amdgcn_s_barrier();
  }

  // ---- fused LSTM epilogue: gate g == fragment n; per-lane ----
  const int hc = bN * 64 + wn * 16 + lr;
  const float vbf = bF[hc], vbi = bI[hc], vbo = bO[hc], vbc = bC[hc];
#pragma unroll
  for (int m = 0; m < 8; ++m) {
    const int rbase = bM * 256 + wm * 128 + m * 16 + hi * 4;
#pragma unroll
    for (int v = 0; v < 4; ++v) {
      const size_t idx = (size_t)(rbase + v) * 2048 + hc;
      float gf = acc[m][0][v] + vbf;
      float gi = acc[m][1][v] + vbi;
      float go = acc[m][2][v] + vbo;
      float gc = acc[m][3][v] + vbc;
      float fg = 1.f / (1.f + __expf(-gf));
      float ig = 1.f / (1.f + __expf(-gi));
      float og = 1.f / (1.f + __expf(-go));
      float ct = 2.f / (1.f + __expf(-2.f * gc)) - 1.f;
      float cn = fg * cin[idx] + ig * ct;
      float hn = og * (2.f / (1.f + __expf(-2.f * cn)) - 1.f);
      hout[idx] = hn;
      cout_[idx] = cn;
    }
  }
}

extern "C" void kernel_launch(void* const* d_in, const int* in_sizes, int n_in,
                              void* d_out, int out_size, void* d_ws, size_t ws_size,
                              hipStream_t stream) {
  const float* x    = (const float*)d_in[0];
  const float* h    = (const float*)d_in[1];
  const float* c    = (const float*)d_in[2];
  const float* w_xf = (const float*)d_in[3];
  const float* w_hf = (const float*)d_in[4];
  const float* b_f  = (const float*)d_in[5];
  const float* w_xi = (const float*)d_in[6];
  const float* w_hi = (const float*)d_in[7];
  const float* b_i  = (const float*)d_in[8];
  const float* w_xo = (const float*)d_in[9];
  const float* w_ho = (const float*)d_in[10];
  const float* b_o  = (const float*)d_in[11];
  const float* w_xc = (const float*)d_in[12];
  const float* w_hc = (const float*)d_in[13];
  const float* b_c  = (const float*)d_in[14];

  float* hout  = (float*)d_out;
  float* cout_ = hout + (size_t)8192 * 2048;

  short* X2 = (short*)d_ws;                       // 64 MiB
  short* W3 = X2 + (size_t)8192 * 4096;           // 64 MiB

  const int packBlocks = (int)(((long)8192 * 4096 / 8) / 256);  // 16384
  pack_x_kernel<<<packBlocks, 256, 0, stream>>>(x, h, X2);
  pack_w_kernel<<<packBlocks, 256, 0, stream>>>(w_xf, w_xi, w_xo, w_xc,
                                                w_hf, w_hi, w_ho, w_hc, W3);

  lstm_fused_gemm<<<1024, 512, 0, stream>>>(X2, W3, c, b_f, b_i, b_o, b_c,
                                            hout, cout_);
}

// Round 4
// 619.191 us; speedup vs baseline: 1.2193x; 1.0432x over previous
//
#include <hip/hip_runtime.h>

// LSTM cell, B=8192, IN=H=2048, fp32 in/out.
// Round 4: m201-faithful quadrant phases. Each phase: 4-or-8 ds_read_b128 +
// 1-2 GLDS stages; barrier; lgkmcnt(0); 16 MFMA (one 64x64 quadrant x K=32);
// barrier. Counted vmcnt(10)/vmcnt(8) per K-tile. No sched_barrier pinning.
// Pack: X2 bf16 [8192][4096] = [x|h];  W3 bf16 [8192][4096] with row
//   j = (hc>>4)*64 + gate*16 + (hc&15)  -> per-wave n-fragment == gate.

typedef __attribute__((ext_vector_type(8))) short short8;
typedef __attribute__((ext_vector_type(8))) __bf16 bf16x8;
typedef __attribute__((ext_vector_type(4))) float f32x4;

#define GLDS(gp, lp)                                                        \
  __builtin_amdgcn_global_load_lds(                                         \
      (const __attribute__((address_space(1))) void*)(gp),                  \
      (__attribute__((address_space(3))) void*)(lp), 16, 0, 0)

__device__ __forceinline__ unsigned short f2bf(float f) {
  unsigned u = __builtin_bit_cast(unsigned, f);
  u = (u + 0x7FFFu + ((u >> 16) & 1u)) >> 16;  // RNE
  return (unsigned short)u;
}

// ---- pack [x | h] -> X2 bf16 [8192][4096] ----
__global__ void pack_x_kernel(const float* __restrict__ x,
                              const float* __restrict__ h,
                              short* __restrict__ X2) {
  long tid = (long)blockIdx.x * blockDim.x + threadIdx.x;
  long flat = tid * 8;
  int row = (int)(flat >> 12);
  int k = (int)(flat & 4095);
  const float* src = (k < 2048) ? (x + (long)row * 2048 + k)
                                : (h + (long)row * 2048 + (k - 2048));
  float4 a = *(const float4*)src;
  float4 b = *(const float4*)(src + 4);
  short8 o;
  o[0] = (short)f2bf(a.x); o[1] = (short)f2bf(a.y);
  o[2] = (short)f2bf(a.z); o[3] = (short)f2bf(a.w);
  o[4] = (short)f2bf(b.x); o[5] = (short)f2bf(b.y);
  o[6] = (short)f2bf(b.z); o[7] = (short)f2bf(b.w);
  *(short8*)(X2 + flat) = o;
}

// ---- pack weights -> W3 bf16 [8192][4096]; row j: hc=(j>>6)*16+(j&15), g=(j>>4)&3 ----
__global__ void pack_w_kernel(const float* __restrict__ wxf, const float* __restrict__ wxi,
                              const float* __restrict__ wxo, const float* __restrict__ wxc,
                              const float* __restrict__ whf, const float* __restrict__ whi,
                              const float* __restrict__ who, const float* __restrict__ whc,
                              short* __restrict__ W3) {
  long tid = (long)blockIdx.x * blockDim.x + threadIdx.x;
  long flat = tid * 8;
  int j = (int)(flat >> 12);
  int k = (int)(flat & 4095);
  int hc = ((j >> 6) << 4) | (j & 15);
  int g = (j >> 4) & 3;
  const float* base;
  if (k < 2048) {
    const float* wx = (g == 0) ? wxf : (g == 1) ? wxi : (g == 2) ? wxo : wxc;
    base = wx + (long)hc * 2048 + k;
  } else {
    const float* wh = (g == 0) ? whf : (g == 1) ? whi : (g == 2) ? who : whc;
    base = wh + (long)hc * 2048 + (k - 2048);
  }
  float4 a = *(const float4*)base;
  float4 b = *(const float4*)(base + 4);
  short8 o;
  o[0] = (short)f2bf(a.x); o[1] = (short)f2bf(a.y);
  o[2] = (short)f2bf(a.z); o[3] = (short)f2bf(a.w);
  o[4] = (short)f2bf(b.x); o[5] = (short)f2bf(b.y);
  o[6] = (short)f2bf(b.z); o[7] = (short)f2bf(b.w);
  *(short8*)(W3 + flat) = o;
}

// ---- 256x256 fused GEMM + LSTM epilogue ----
// LDS per buffer: q0 A-kh0 @0, q1 B-kh0 @16K, q2 A-kh1 @32K, q3 B-kh1 @48K.
// 16B-chunk swizzle: slot ^= (r>>1)&3 (involution on source + ds_read).
// Stage schedule (per tile t): ph0: q2,q3(t+1)->nxt; ph1: q1(t+2)->cur;
// ph2: q0(t+2)->cur; ph3: none.  vmcnt(10) @ph1-end, vmcnt(8) @ph3-end.
__global__ __launch_bounds__(512, 2) void lstm_fused_gemm(
    const short* __restrict__ X2, const short* __restrict__ W3,
    const float* __restrict__ cin,
    const float* __restrict__ bF, const float* __restrict__ bI,
    const float* __restrict__ bO, const float* __restrict__ bC,
    float* __restrict__ hout, float* __restrict__ cout_) {
  __shared__ __align__(16) short lds[65536];  // 128 KiB

  const int tid = threadIdx.x;
  const int lane = tid & 63;
  const int w = tid >> 6;        // 0..7
  const int wm = w >> 2;         // 0..1  (M half, 128 rows)
  const int wn = w & 3;          // 0..3  (N quarter, 64 cols)

  // T1: XCD-aware swizzle (1024 % 8 == 0 -> bijective).
  const int bid = blockIdx.x;
  const int wg = (bid & 7) * 128 + (bid >> 3);
  const int bM = wg >> 5;        // 0..31
  const int bN = wg & 31;        // 0..31

  // --- staging geometry ---
  const int ci = w * 64 + lane;
  const int r0 = ci >> 2;                       // 0..127
  const int ss = (ci & 3) ^ ((r0 >> 1) & 3);    // pre-swizzled source slot
  const short* aRow0 = X2 + ((size_t)(bM * 256 + r0)) * 4096 + ss * 8;
  const short* aRow1 = aRow0 + (size_t)128 * 4096;
  const short* bRow0 = W3 + ((size_t)(bN * 256 + r0)) * 4096 + ss * 8;
  const short* bRow1 = bRow0 + (size_t)128 * 4096;
  const int wOff = w * 1024;

#define STAGE2(q, tt, bb) do {                                               \
    const int _kh = (q) >> 1;                                                \
    const short* _g0; const short* _g1;                                      \
    if ((q) == 0 || (q) == 2) {                                              \
      _g0 = aRow0 + (tt) * 64 + _kh * 32;                                    \
      _g1 = aRow1 + (tt) * 64 + _kh * 32;                                    \
    } else {                                                                 \
      _g0 = bRow0 + (tt) * 64 + _kh * 32;                                    \
      _g1 = bRow1 + (tt) * 64 + _kh * 32;                                    \
    }                                                                        \
    char* _l0 = (char*)lds + (bb) * 65536 + (q) * 16384 + wOff;              \
    GLDS(_g0, _l0);                                                          \
    GLDS(_g1, _l0 + 8192);                                                   \
  } while (0)

  // --- ds_read geometry ---
  const int lr = lane & 15, hi = lane >> 4;
  const int swz = ((hi ^ ((lr >> 1) & 3)) << 4);
  const int aoff = wm * 8192 + lr * 64 + swz;          // + m*1024 (+32768 kh1)
  const int boff = 16384 + wn * 4096 + lr * 64 + swz;  // + n*1024 (+32768 kh1)

#define LDSRD(off) (*(const bf16x8*)((const char*)lds + (off)))
#define MFMA_(a, b, c) __builtin_amdgcn_mfma_f32_16x16x32_bf16((a), (b), (c), 0, 0, 0)

  f32x4 acc[8][4] = {};  // [m][n==gate]

  // --- prologue: q0-q3(t0)->buf0, q0,q1(t1)->buf1 (12 GLDS); wait q0,q1(t0) ---
  STAGE2(0, 0, 0); STAGE2(1, 0, 0); STAGE2(2, 0, 0); STAGE2(3, 0, 0);
  STAGE2(0, 1, 1); STAGE2(1, 1, 1);
  asm volatile("s_waitcnt vmcnt(8)" ::: "memory");
  __builtin_amdgcn_s_barrier();

#pragma unroll 2
  for (int t = 0; t < 64; ++t) {
    const int cur = t & 1, nxt = cur ^ 1;
    const int bo = cur << 16;
    const int t1 = (t + 1) & 63;   // wrapped dummy stages keep vmcnt uniform
    const int t2 = (t + 2) & 63;
    bf16x8 a[4], b[4];

    // ---- ph0 (mh0, kh0): 8 reads; stage q2,q3(t+1)->nxt; MFMA acc[0..3][*]
#pragma unroll
    for (int i = 0; i < 4; ++i) a[i] = LDSRD(bo + aoff + i * 1024);
#pragma unroll
    for (int n = 0; n < 4; ++n) b[n] = LDSRD(bo + boff + n * 1024);
    STAGE2(2, t1, nxt);
    STAGE2(3, t1, nxt);
    __builtin_amdgcn_s_barrier();
    asm volatile("s_waitcnt lgkmcnt(0)" ::: "memory");
    __builtin_amdgcn_s_setprio(1);
#pragma unroll
    for (int n = 0; n < 4; ++n)
#pragma unroll
      for (int i = 0; i < 4; ++i) acc[i][n] = MFMA_(a[i], b[n], acc[i][n]);
    __builtin_amdgcn_s_setprio(0);
    __builtin_amdgcn_s_barrier();

    // ---- ph1 (mh1, kh0): 4 reads (B reused in regs); stage q1(t+2)->cur
#pragma unroll
    for (int i = 0; i < 4; ++i) a[i] = LDSRD(bo + aoff + (4 + i) * 1024);
    STAGE2(1, t2, cur);
    __builtin_amdgcn_s_barrier();
    asm volatile("s_waitcnt lgkmcnt(0)" ::: "memory");
    __builtin_amdgcn_s_setprio(1);
#pragma unroll
    for (int n = 0; n < 4; ++n)
#pragma unroll
      for (int i = 0; i < 4; ++i) acc[4 + i][n] = MFMA_(a[i], b[n], acc[4 + i][n]);
    __builtin_amdgcn_s_setprio(0);
    asm volatile("s_waitcnt vmcnt(10)" ::: "memory");  // q2,q3(t) landed
    __builtin_amdgcn_s_barrier();

    // ---- ph2 (mh0, kh1): 8 reads; stage q0(t+2)->cur; MFMA acc[0..3][*]
#pragma unroll
    for (int i = 0; i < 4; ++i) a[i] = LDSRD(bo + aoff + 32768 + i * 1024);
#pragma unroll
    for (int n = 0; n < 4; ++n) b[n] = LDSRD(bo + boff + 32768 + n * 1024);
    STAGE2(0, t2, cur);
    __builtin_amdgcn_s_barrier();
    asm volatile("s_waitcnt lgkmcnt(0)" ::: "memory");
    __builtin_amdgcn_s_setprio(1);
#pragma unroll
    for (int n = 0; n < 4; ++n)
#pragma unroll
      for (int i = 0; i < 4; ++i) acc[i][n] = MFMA_(a[i], b[n], acc[i][n]);
    __builtin_amdgcn_s_setprio(0);
    __builtin_amdgcn_s_barrier();

    // ---- ph3 (mh1, kh1): 4 reads; no stage; MFMA acc[4..7][*]; vmcnt(8)
#pragma unroll
    for (int i = 0; i < 4; ++i) a[i] = LDSRD(bo + aoff + 32768 + (4 + i) * 1024);
    __builtin_amdgcn_s_barrier();
    asm volatile("s_waitcnt lgkmcnt(0)" ::: "memory");
    __builtin_amdgcn_s_setprio(1);
#pragma unroll
    for (int n = 0; n < 4; ++n)
#pragma unroll
      for (int i = 0; i < 4; ++i) acc[4 + i][n] = MFMA_(a[i], b[n], acc[4 + i][n]);
    __builtin_amdgcn_s_setprio(0);
    asm volatile("s_waitcnt vmcnt(8)" ::: "memory");   // q0,q1(t+1) landed
    __builtin_amdgcn_s_barrier();
  }

  // ---- fused LSTM epilogue: gate g == fragment n; per-lane ----
  const int hc = bN * 64 + wn * 16 + lr;
  const float vbf = bF[hc], vbi = bI[hc], vbo = bO[hc], vbc = bC[hc];
#pragma unroll
  for (int m = 0; m < 8; ++m) {
    const int rbase = bM * 256 + wm * 128 + m * 16 + hi * 4;
#pragma unroll
    for (int v = 0; v < 4; ++v) {
      const size_t idx = (size_t)(rbase + v) * 2048 + hc;
      float gf = acc[m][0][v] + vbf;
      float gi = acc[m][1][v] + vbi;
      float go = acc[m][2][v] + vbo;
      float gc = acc[m][3][v] + vbc;
      float fg = 1.f / (1.f + __expf(-gf));
      float ig = 1.f / (1.f + __expf(-gi));
      float og = 1.f / (1.f + __expf(-go));
      float ct = 2.f / (1.f + __expf(-2.f * gc)) - 1.f;
      float cn = fg * cin[idx] + ig * ct;
      float hn = og * (2.f / (1.f + __expf(-2.f * cn)) - 1.f);
      hout[idx] = hn;
      cout_[idx] = cn;
    }
  }
}

extern "C" void kernel_launch(void* const* d_in, const int* in_sizes, int n_in,
                              void* d_out, int out_size, void* d_ws, size_t ws_size,
                              hipStream_t stream) {
  const float* x    = (const float*)d_in[0];
  const float* h    = (const float*)d_in[1];
  const float* c    = (const float*)d_in[2];
  const float* w_xf = (const float*)d_in[3];
  const float* w_hf = (const float*)d_in[4];
  const float* b_f  = (const float*)d_in[5];
  const float* w_xi = (const float*)d_in[6];
  const float* w_hi = (const float*)d_in[7];
  const float* b_i  = (const float*)d_in[8];
  const float* w_xo = (const float*)d_in[9];
  const float* w_ho = (const float*)d_in[10];
  const float* b_o  = (const float*)d_in[11];
  const float* w_xc = (const float*)d_in[12];
  const float* w_hc = (const float*)d_in[13];
  const float* b_c  = (const float*)d_in[14];

  float* hout  = (float*)d_out;
  float* cout_ = hout + (size_t)8192 * 2048;

  short* X2 = (short*)d_ws;                       // 64 MiB
  short* W3 = X2 + (size_t)8192 * 4096;           // 64 MiB

  const int packBlocks = (int)(((long)8192 * 4096 / 8) / 256);  // 16384
  pack_x_kernel<<<packBlocks, 256, 0, stream>>>(x, h, X2);
  pack_w_kernel<<<packBlocks, 256, 0, stream>>>(w_xf, w_xi, w_xo, w_xc,
                                                w_hf, w_hi, w_ho, w_hc, W3);

  lstm_fused_gemm<<<1024, 512, 0, stream>>>(X2, W3, c, b_f, b_i, b_o, b_c,
                                            hout, cout_);
}

// Round 5
// 542.410 us; speedup vs baseline: 1.3919x; 1.1416x over previous
//
#include <hip/hip_runtime.h>

// LSTM cell, B=8192, IN=H=2048, fp32 in/out.
// Round 5: single-barrier phases (4 barriers/tile, was 8). Stage schedule
// re-derived so every overwrite is >=2 phases after the region's last read
// (provably race-free at max skew 1 phase). Counted vmcnt(8)/vmcnt(4).
// Within-XCD 2D super-tile for B-panel L2/L3 locality. Fused LSTM epilogue.
// Pack: X2 bf16 [8192][4096] = [x|h];  W3 bf16 [8192][4096] with row
//   j = (hc>>4)*64 + gate*16 + (hc&15)  -> per-wave n-fragment == gate.

typedef __attribute__((ext_vector_type(8))) short short8;
typedef __attribute__((ext_vector_type(8))) __bf16 bf16x8;
typedef __attribute__((ext_vector_type(4))) float f32x4;

#define GLDS(gp, lp)                                                        \
  __builtin_amdgcn_global_load_lds(                                         \
      (const __attribute__((address_space(1))) void*)(gp),                  \
      (__attribute__((address_space(3))) void*)(lp), 16, 0, 0)

__device__ __forceinline__ unsigned short f2bf(float f) {
  unsigned u = __builtin_bit_cast(unsigned, f);
  u = (u + 0x7FFFu + ((u >> 16) & 1u)) >> 16;  // RNE
  return (unsigned short)u;
}

// ---- pack [x | h] -> X2 bf16 [8192][4096] ----
__global__ void pack_x_kernel(const float* __restrict__ x,
                              const float* __restrict__ h,
                              short* __restrict__ X2) {
  long tid = (long)blockIdx.x * blockDim.x + threadIdx.x;
  long flat = tid * 8;
  int row = (int)(flat >> 12);
  int k = (int)(flat & 4095);
  const float* src = (k < 2048) ? (x + (long)row * 2048 + k)
                                : (h + (long)row * 2048 + (k - 2048));
  float4 a = *(const float4*)src;
  float4 b = *(const float4*)(src + 4);
  short8 o;
  o[0] = (short)f2bf(a.x); o[1] = (short)f2bf(a.y);
  o[2] = (short)f2bf(a.z); o[3] = (short)f2bf(a.w);
  o[4] = (short)f2bf(b.x); o[5] = (short)f2bf(b.y);
  o[6] = (short)f2bf(b.z); o[7] = (short)f2bf(b.w);
  *(short8*)(X2 + flat) = o;
}

// ---- pack weights -> W3 bf16 [8192][4096]; row j: hc=(j>>6)*16+(j&15), g=(j>>4)&3 ----
__global__ void pack_w_kernel(const float* __restrict__ wxf, const float* __restrict__ wxi,
                              const float* __restrict__ wxo, const float* __restrict__ wxc,
                              const float* __restrict__ whf, const float* __restrict__ whi,
                              const float* __restrict__ who, const float* __restrict__ whc,
                              short* __restrict__ W3) {
  long tid = (long)blockIdx.x * blockDim.x + threadIdx.x;
  long flat = tid * 8;
  int j = (int)(flat >> 12);
  int k = (int)(flat & 4095);
  int hc = ((j >> 6) << 4) | (j & 15);
  int g = (j >> 4) & 3;
  const float* base;
  if (k < 2048) {
    const float* wx = (g == 0) ? wxf : (g == 1) ? wxi : (g == 2) ? wxo : wxc;
    base = wx + (long)hc * 2048 + k;
  } else {
    const float* wh = (g == 0) ? whf : (g == 1) ? whi : (g == 2) ? who : whc;
    base = wh + (long)hc * 2048 + (k - 2048);
  }
  float4 a = *(const float4*)base;
  float4 b = *(const float4*)(base + 4);
  short8 o;
  o[0] = (short)f2bf(a.x); o[1] = (short)f2bf(a.y);
  o[2] = (short)f2bf(a.z); o[3] = (short)f2bf(a.w);
  o[4] = (short)f2bf(b.x); o[5] = (short)f2bf(b.y);
  o[6] = (short)f2bf(b.z); o[7] = (short)f2bf(b.w);
  *(short8*)(W3 + flat) = o;
}

// ---- 256x256 fused GEMM + LSTM epilogue ----
// LDS per buffer: q0 A-kh0 @0, q1 B-kh0 @16K, q2 A-kh1 @32K, q3 B-kh1 @48K.
// 16B-chunk swizzle: slot ^= (r>>1)&3 (involution on source + ds_read).
// Region last-read phases: q0:ph1, q1:ph0, q2:ph3, q3:ph2.
// Stage (all -> t+1, buf nxt): ph0: q0,q1,q3 (dist 3,4,2); ph1: q2 (dist 2).
// Gates: vmcnt(8) end-ph1 (q2,q3 of t landed); vmcnt(4) end-ph3 (q0,q1 of
// t+1 landed). One barrier per phase, between read/stage issue and MFMA.
__global__ __launch_bounds__(512, 2) void lstm_fused_gemm(
    const short* __restrict__ X2, const short* __restrict__ W3,
    const float* __restrict__ cin,
    const float* __restrict__ bF, const float* __restrict__ bI,
    const float* __restrict__ bO, const float* __restrict__ bC,
    float* __restrict__ hout, float* __restrict__ cout_) {
  __shared__ __align__(16) short lds[65536];  // 128 KiB

  const int tid = threadIdx.x;
  const int lane = tid & 63;
  const int w = tid >> 6;        // 0..7
  const int wm = w >> 2;         // 0..1  (M half, 128 rows)
  const int wn = w & 3;          // 0..3  (N quarter, 64 cols)

  // T1 + within-XCD 2D super-tile: bid = xcd + 8*m4 + 32*bN (bijective).
  // Co-resident 32 blocks/XCD cover 4 M-rows x 8 N-cols -> B set 16 MB.
  const int bid = blockIdx.x;
  const int bM = (bid & 7) * 4 + ((bid >> 3) & 3);  // 0..31
  const int bN = bid >> 5;                          // 0..31

  // --- staging geometry ---
  const int ci = w * 64 + lane;
  const int r0 = ci >> 2;                       // 0..127
  const int ss = (ci & 3) ^ ((r0 >> 1) & 3);    // pre-swizzled source slot
  const short* aRow0 = X2 + ((size_t)(bM * 256 + r0)) * 4096 + ss * 8;
  const short* aRow1 = aRow0 + (size_t)128 * 4096;
  const short* bRow0 = W3 + ((size_t)(bN * 256 + r0)) * 4096 + ss * 8;
  const short* bRow1 = bRow0 + (size_t)128 * 4096;
  const int wOff = w * 1024;

#define STAGE2(q, tt, bb) do {                                               \
    const int _kh = (q) >> 1;                                                \
    const short* _g0; const short* _g1;                                      \
    if ((q) == 0 || (q) == 2) {                                              \
      _g0 = aRow0 + (tt) * 64 + _kh * 32;                                    \
      _g1 = aRow1 + (tt) * 64 + _kh * 32;                                    \
    } else {                                                                 \
      _g0 = bRow0 + (tt) * 64 + _kh * 32;                                    \
      _g1 = bRow1 + (tt) * 64 + _kh * 32;                                    \
    }                                                                        \
    char* _l0 = (char*)lds + (bb) * 65536 + (q) * 16384 + wOff;              \
    GLDS(_g0, _l0);                                                          \
    GLDS(_g1, _l0 + 8192);                                                   \
  } while (0)

  // --- ds_read geometry ---
  const int lr = lane & 15, hi = lane >> 4;
  const int swz = ((hi ^ ((lr >> 1) & 3)) << 4);
  const int aoff = wm * 8192 + lr * 64 + swz;          // + m*1024 (+32768 kh1)
  const int boff = 16384 + wn * 4096 + lr * 64 + swz;  // + n*1024 (+32768 kh1)

#define LDSRD(off) (*(const bf16x8*)((const char*)lds + (off)))
#define MFMA_(a, b, c) __builtin_amdgcn_mfma_f32_16x16x32_bf16((a), (b), (c), 0, 0, 0)

  f32x4 acc[8][4] = {};  // [m][n==gate]

  // --- prologue: all 4 regions of tile 0 -> buf0; drain; barrier ---
  STAGE2(0, 0, 0); STAGE2(1, 0, 0); STAGE2(3, 0, 0); STAGE2(2, 0, 0);
  asm volatile("s_waitcnt vmcnt(0)" ::: "memory");
  __builtin_amdgcn_s_barrier();

#pragma unroll 2
  for (int t = 0; t < 64; ++t) {
    const int cur = t & 1, nxt = cur ^ 1;
    const int bo = cur << 16;
    const int t1 = (t + 1) & 63;   // t=63 stages dummy data (never read; safe)
    bf16x8 a[4], b[4];

    // ---- ph0 (mh0, kh0): 8 reads; stage q0,q1,q3(t+1)->nxt ----
#pragma unroll
    for (int i = 0; i < 4; ++i) a[i] = LDSRD(bo + aoff + i * 1024);
#pragma unroll
    for (int n = 0; n < 4; ++n) b[n] = LDSRD(bo + boff + n * 1024);
    STAGE2(0, t1, nxt);
    STAGE2(1, t1, nxt);
    STAGE2(3, t1, nxt);
    __builtin_amdgcn_s_barrier();
    asm volatile("s_waitcnt lgkmcnt(0)" ::: "memory");
    __builtin_amdgcn_s_setprio(1);
#pragma unroll
    for (int n = 0; n < 4; ++n)
#pragma unroll
      for (int i = 0; i < 4; ++i) acc[i][n] = MFMA_(a[i], b[n], acc[i][n]);
    __builtin_amdgcn_s_setprio(0);

    // ---- ph1 (mh1, kh0): 4 reads (B reused in regs); stage q2(t+1)->nxt ----
#pragma unroll
    for (int i = 0; i < 4; ++i) a[i] = LDSRD(bo + aoff + (4 + i) * 1024);
    STAGE2(2, t1, nxt);
    __builtin_amdgcn_s_barrier();
    asm volatile("s_waitcnt lgkmcnt(0)" ::: "memory");
    __builtin_amdgcn_s_setprio(1);
#pragma unroll
    for (int n = 0; n < 4; ++n)
#pragma unroll
      for (int i = 0; i < 4; ++i) acc[4 + i][n] = MFMA_(a[i], b[n], acc[4 + i][n]);
    __builtin_amdgcn_s_setprio(0);
    asm volatile("s_waitcnt vmcnt(8)" ::: "memory");   // q2,q3(t) landed

    // ---- ph2 (mh0, kh1): 8 reads; no stage ----
#pragma unroll
    for (int i = 0; i < 4; ++i) a[i] = LDSRD(bo + aoff + 32768 + i * 1024);
#pragma unroll
    for (int n = 0; n < 4; ++n) b[n] = LDSRD(bo + boff + 32768 + n * 1024);
    __builtin_amdgcn_s_barrier();
    asm volatile("s_waitcnt lgkmcnt(0)" ::: "memory");
    __builtin_amdgcn_s_setprio(1);
#pragma unroll
    for (int n = 0; n < 4; ++n)
#pragma unroll
      for (int i = 0; i < 4; ++i) acc[i][n] = MFMA_(a[i], b[n], acc[i][n]);
    __builtin_amdgcn_s_setprio(0);

    // ---- ph3 (mh1, kh1): 4 reads; no stage ----
#pragma unroll
    for (int i = 0; i < 4; ++i) a[i] = LDSRD(bo + aoff + 32768 + (4 + i) * 1024);
    __builtin_amdgcn_s_barrier();
    asm volatile("s_waitcnt lgkmcnt(0)" ::: "memory");
    __builtin_amdgcn_s_setprio(1);
#pragma unroll
    for (int n = 0; n < 4; ++n)
#pragma unroll
      for (int i = 0; i < 4; ++i) acc[4 + i][n] = MFMA_(a[i], b[n], acc[4 + i][n]);
    __builtin_amdgcn_s_setprio(0);
    asm volatile("s_waitcnt vmcnt(4)" ::: "memory");   // q0,q1(t+1) landed
  }

  // ---- fused LSTM epilogue: gate g == fragment n; per-lane ----
  const int hc = bN * 64 + wn * 16 + lr;
  const float vbf = bF[hc], vbi = bI[hc], vbo = bO[hc], vbc = bC[hc];
#pragma unroll
  for (int m = 0; m < 8; ++m) {
    const int rbase = bM * 256 + wm * 128 + m * 16 + hi * 4;
#pragma unroll
    for (int v = 0; v < 4; ++v) {
      const size_t idx = (size_t)(rbase + v) * 2048 + hc;
      float gf = acc[m][0][v] + vbf;
      float gi = acc[m][1][v] + vbi;
      float go = acc[m][2][v] + vbo;
      float gc = acc[m][3][v] + vbc;
      float fg = 1.f / (1.f + __expf(-gf));
      float ig = 1.f / (1.f + __expf(-gi));
      float og = 1.f / (1.f + __expf(-go));
      float ct = 2.f / (1.f + __expf(-2.f * gc)) - 1.f;
      float cn = fg * cin[idx] + ig * ct;
      float hn = og * (2.f / (1.f + __expf(-2.f * cn)) - 1.f);
      hout[idx] = hn;
      cout_[idx] = cn;
    }
  }
}

extern "C" void kernel_launch(void* const* d_in, const int* in_sizes, int n_in,
                              void* d_out, int out_size, void* d_ws, size_t ws_size,
                              hipStream_t stream) {
  const float* x    = (const float*)d_in[0];
  const float* h    = (const float*)d_in[1];
  const float* c    = (const float*)d_in[2];
  const float* w_xf = (const float*)d_in[3];
  const float* w_hf = (const float*)d_in[4];
  const float* b_f  = (const float*)d_in[5];
  const float* w_xi = (const float*)d_in[6];
  const float* w_hi = (const float*)d_in[7];
  const float* b_i  = (const float*)d_in[8];
  const float* w_xo = (const float*)d_in[9];
  const float* w_ho = (const float*)d_in[10];
  const float* b_o  = (const float*)d_in[11];
  const float* w_xc = (const float*)d_in[12];
  const float* w_hc = (const float*)d_in[13];
  const float* b_c  = (const float*)d_in[14];

  float* hout  = (float*)d_out;
  float* cout_ = hout + (size_t)8192 * 2048;

  short* X2 = (short*)d_ws;                       // 64 MiB
  short* W3 = X2 + (size_t)8192 * 4096;           // 64 MiB

  const int packBlocks = (int)(((long)8192 * 4096 / 8) / 256);  // 16384
  pack_x_kernel<<<packBlocks, 256, 0, stream>>>(x, h, X2);
  pack_w_kernel<<<packBlocks, 256, 0, stream>>>(w_xf, w_xi, w_xo, w_xc,
                                                w_hf, w_hi, w_ho, w_hc, W3);

  lstm_fused_gemm<<<1024, 512, 0, stream>>>(X2, W3, c, b_f, b_i, b_o, b_c,
                                            hout, cout_);
}